// Round 3
// baseline (1001.782 us; speedup 1.0000x reference)
//
#include <hip/hip_runtime.h>
#include <hip/hip_bf16.h>

// Problem constants (match reference)
constexpr int N    = 8192;     // nodes
constexpr int E    = 131072;   // node-graph edges == trace rows
constexpr int E2   = 524288;   // line-graph edges

constexpr size_t XT_OFF  = (size_t)N * 128;            // 1048576
constexpr size_t XLG_OFF = XT_OFF + (size_t)E * 128;   // 17825792

__device__ __forceinline__ float b2f(__hip_bfloat16 x) { return __bfloat162float(x); }
__device__ __forceinline__ __hip_bfloat16 f2b(float x) { return __float2bfloat16(x); }

// ---------------------------------------------------------------------------
// CSR build: histogram -> single-block chunked scan -> scatter
__global__ void k_hist(const int* __restrict__ dst, int* __restrict__ cnt, int nE)
{
    int i = blockIdx.x * 256 + threadIdx.x;
    if (i < nE) atomicAdd(&cnt[dst[i]], 1);
}

// exclusive scan of cnt[0..n) into off[0..n] (off[n]=total) and cur[0..n).
// launch <<<1,256>>>; n must be a multiple of 8192.
__global__ __launch_bounds__(256) void k_scan(
    const int* __restrict__ cnt, int* __restrict__ off, int* __restrict__ cur, int n)
{
    __shared__ int tile[8192];
    __shared__ int chunk[257];
    int carry = 0;
    for (int base = 0; base < n; base += 8192) {
        for (int i = threadIdx.x; i < 8192; i += 256) tile[i] = cnt[base + i];
        __syncthreads();
        const int st = threadIdx.x * 32;
        int s = 0;
        for (int k = 0; k < 32; ++k) { int v = tile[st + k]; tile[st + k] = s; s += v; }
        chunk[threadIdx.x] = s;
        __syncthreads();
        if (threadIdx.x == 0) {
            int t = 0;
            for (int c = 0; c < 256; ++c) { int v = chunk[c]; chunk[c] = t; t += v; }
            chunk[256] = t;
        }
        __syncthreads();
        const int add = carry + chunk[threadIdx.x];
        for (int k = 0; k < 32; ++k) {
            int o = add + tile[st + k];
            off[base + st + k] = o;
            cur[base + st + k] = o;
        }
        carry += chunk[256];
        __syncthreads();   // protect tile/chunk before next iteration
    }
    if (threadIdx.x == 0) off[n] = carry;
}

__global__ void k_scatter(const int* __restrict__ dst, int* __restrict__ cur,
                          int* __restrict__ eid, int nE)
{
    int i = blockIdx.x * 256 + threadIdx.x;
    if (i < nE) {
        int pos = atomicAdd(&cur[dst[i]], 1);
        eid[pos] = i;
    }
}

// ---------------------------------------------------------------------------
// K1: xl_n/xr_n = concat(x_node,x_log) @ {Wl,Wr} + {bl,br}   [N,256] -> bf16
__global__ __launch_bounds__(256) void k_node_gemm(
    const float* __restrict__ x_node, const float* __restrict__ x_log,
    const float* __restrict__ Wl, const float* __restrict__ bl,
    const float* __restrict__ Wr, const float* __restrict__ br,
    __hip_bfloat16* __restrict__ xl, __hip_bfloat16* __restrict__ xr)
{
    __shared__ float rows[8][256];
    const int n0 = blockIdx.x * 8;
    const int tid = threadIdx.x;
    for (int i = tid; i < 8 * 256; i += 256) {
        int r = i >> 8, k = i & 255;
        float v = (k < 128) ? x_node[(size_t)(n0 + r) * 128 + k]
                            : x_log[(size_t)(n0 + r) * 128 + (k - 128)];
        rows[r][k] = v;
    }
    __syncthreads();
    const int j = tid;
    float accL[8], accR[8];
    const float blv = bl[j], brv = br[j];
#pragma unroll
    for (int r = 0; r < 8; ++r) { accL[r] = blv; accR[r] = brv; }
    for (int k0 = 0; k0 < 256; k0 += 4) {
        float wl0 = Wl[(size_t)(k0 + 0) * 256 + j];
        float wl1 = Wl[(size_t)(k0 + 1) * 256 + j];
        float wl2 = Wl[(size_t)(k0 + 2) * 256 + j];
        float wl3 = Wl[(size_t)(k0 + 3) * 256 + j];
        float wr0 = Wr[(size_t)(k0 + 0) * 256 + j];
        float wr1 = Wr[(size_t)(k0 + 1) * 256 + j];
        float wr2 = Wr[(size_t)(k0 + 2) * 256 + j];
        float wr3 = Wr[(size_t)(k0 + 3) * 256 + j];
#pragma unroll
        for (int r = 0; r < 8; ++r) {
            float4 v = *reinterpret_cast<const float4*>(&rows[r][k0]);
            accL[r] += v.x * wl0 + v.y * wl1 + v.z * wl2 + v.w * wl3;
            accR[r] += v.x * wr0 + v.y * wr1 + v.z * wr2 + v.w * wr3;
        }
    }
#pragma unroll
    for (int r = 0; r < 8; ++r) {
        xl[(size_t)(n0 + r) * 256 + j] = f2b(accL[r]);
        xr[(size_t)(n0 + r) * 256 + j] = f2b(accR[r]);
    }
}

// ---------------------------------------------------------------------------
// K2: xl_e = trace@Wl2+bl2 (bf16, ws) and xr_e = trace@Wr2+br2 (f32 -> out XT region)
__global__ __launch_bounds__(128) void k_trace_gemm(
    const float* __restrict__ x_trace,
    const float* __restrict__ Wl, const float* __restrict__ bl,
    const float* __restrict__ Wr, const float* __restrict__ br,
    __hip_bfloat16* __restrict__ xl, float* __restrict__ xr_out)
{
    __shared__ float rows[8][128];
    const int e0 = blockIdx.x * 8;
    const int tid = threadIdx.x;
    for (int i = tid; i < 8 * 128; i += 128) {
        int r = i >> 7, k = i & 127;
        rows[r][k] = x_trace[(size_t)(e0 + r) * 128 + k];
    }
    __syncthreads();
    const int j = tid;
    float accL[8], accR[8];
    const float blv = bl[j], brv = br[j];
#pragma unroll
    for (int r = 0; r < 8; ++r) { accL[r] = blv; accR[r] = brv; }
    for (int k0 = 0; k0 < 128; k0 += 4) {
        float wl0 = Wl[(size_t)(k0 + 0) * 128 + j];
        float wl1 = Wl[(size_t)(k0 + 1) * 128 + j];
        float wl2 = Wl[(size_t)(k0 + 2) * 128 + j];
        float wl3 = Wl[(size_t)(k0 + 3) * 128 + j];
        float wr0 = Wr[(size_t)(k0 + 0) * 128 + j];
        float wr1 = Wr[(size_t)(k0 + 1) * 128 + j];
        float wr2 = Wr[(size_t)(k0 + 2) * 128 + j];
        float wr3 = Wr[(size_t)(k0 + 3) * 128 + j];
#pragma unroll
        for (int r = 0; r < 8; ++r) {
            float4 v = *reinterpret_cast<const float4*>(&rows[r][k0]);
            accL[r] += v.x * wl0 + v.y * wl1 + v.z * wl2 + v.w * wl3;
            accR[r] += v.x * wr0 + v.y * wr1 + v.z * wr2 + v.w * wr3;
        }
    }
#pragma unroll
    for (int r = 0; r < 8; ++r) {
        xl[(size_t)(e0 + r) * 128 + j] = f2b(accL[r]);
        xr_out[(size_t)(e0 + r) * 128 + j] = accR[r];   // f32 staged in xt output region
    }
}

// ---------------------------------------------------------------------------
// K3: fused e-GEMM (trace@We) + layer-1 logits. 16 edges/block, 256 thr.
__global__ __launch_bounds__(256) void k_edge_alpha1(
    const float* __restrict__ x_trace,
    const int* __restrict__ adj,          // [2,E] src then dst
    const __hip_bfloat16* __restrict__ xl, const __hip_bfloat16* __restrict__ xr,
    const float* __restrict__ We, const float* __restrict__ att,
    float* __restrict__ alpha)
{
    __shared__ float rows[16][128];
    __shared__ int ss[16], dd[16];
    const int e0 = blockIdx.x * 16;
    const int tid = threadIdx.x;
    for (int i = tid; i < 16 * 128; i += 256) {
        int t = i >> 7, k = i & 127;
        rows[t][k] = x_trace[(size_t)(e0 + t) * 128 + k];
    }
    if (tid < 16) { ss[tid] = adj[e0 + tid]; dd[tid] = adj[E + e0 + tid]; }
    __syncthreads();
    const int j = tid;
    float acc[16];
#pragma unroll
    for (int t = 0; t < 16; ++t) acc[t] = 0.f;
    for (int k0 = 0; k0 < 128; k0 += 4) {
        float w0 = We[(size_t)(k0 + 0) * 256 + j];
        float w1 = We[(size_t)(k0 + 1) * 256 + j];
        float w2 = We[(size_t)(k0 + 2) * 256 + j];
        float w3 = We[(size_t)(k0 + 3) * 256 + j];
#pragma unroll
        for (int t = 0; t < 16; ++t) {
            float4 v = *reinterpret_cast<const float4*>(&rows[t][k0]);
            acc[t] += v.x * w0 + v.y * w1 + v.z * w2 + v.w * w3;
        }
    }
    const float av = att[j];
    const int h = tid >> 6;   // wave id == head id (C=64)
#pragma unroll
    for (int t = 0; t < 16; ++t) {
        const int s = ss[t], d = dd[t];
        float m = acc[t] + b2f(xl[(size_t)s * 256 + j]) + b2f(xr[(size_t)d * 256 + j]);
        m = m > 0.f ? m : 0.2f * m;
        float p = m * av;
        p += __shfl_down(p, 32);
        p += __shfl_down(p, 16);
        p += __shfl_down(p, 8);
        p += __shfl_down(p, 4);
        p += __shfl_down(p, 2);
        p += __shfl_down(p, 1);
        if ((tid & 63) == 0) alpha[(size_t)(e0 + t) * 4 + h] = p;
    }
}

// ---------------------------------------------------------------------------
// K4: layer-1 fused online-softmax + gather-aggregate. One node per block.
__global__ __launch_bounds__(256) void k_fused1(
    const int* __restrict__ adj,          // src = adj[e]
    const int* __restrict__ off, const int* __restrict__ eid,
    const float* __restrict__ alpha,
    const __hip_bfloat16* __restrict__ xl,
    const float* __restrict__ bias,
    float* __restrict__ out)
{
    const int n = blockIdx.x;
    const int j = threadIdx.x;
    const int h = j >> 6;
    const int beg = off[n], end = off[n + 1];
    float mx = -INFINITY, den = 0.f, acc = 0.f;
    for (int i = beg; i < end; ++i) {
        const int e = eid[i];
        const int s = adj[e];
        const float pe = alpha[(size_t)e * 4 + h];
        const float mnew = fmaxf(mx, pe);
        const float sc = __expf(mx - mnew);
        const float ex = __expf(pe - mnew);
        const float feat = b2f(xl[(size_t)s * 256 + j]);
        den = den * sc + ex;
        acc = acc * sc + ex * feat;
        mx = mnew;
    }
    const float v = acc / (den + 1e-16f) + bias[j];
    if (j < 128) out[(size_t)n * 128 + j] = v;
    else         out[XLG_OFF + (size_t)n * 128 + (j - 128)] = v;
}

// ---------------------------------------------------------------------------
// K5: proj = node_out @ e2n_We  [N,128] bf16  (edge-feature transform commuted)
__global__ __launch_bounds__(128) void k_proj_gemm(
    const float* __restrict__ out_node, const float* __restrict__ We,
    __hip_bfloat16* __restrict__ proj)
{
    __shared__ float rows[8][256];
    const int n0 = blockIdx.x * 8;
    const int tid = threadIdx.x;
    for (int i = tid; i < 8 * 256; i += 128) {
        int r = i >> 8, k = i & 255;
        float v = (k < 128) ? out_node[(size_t)(n0 + r) * 128 + k]
                            : out_node[XLG_OFF + (size_t)(n0 + r) * 128 + (k - 128)];
        rows[r][k] = v;
    }
    __syncthreads();
    const int j = tid;
    float acc[8];
#pragma unroll
    for (int r = 0; r < 8; ++r) acc[r] = 0.f;
    for (int k0 = 0; k0 < 256; k0 += 4) {
        float w0 = We[(size_t)(k0 + 0) * 128 + j];
        float w1 = We[(size_t)(k0 + 1) * 128 + j];
        float w2 = We[(size_t)(k0 + 2) * 128 + j];
        float w3 = We[(size_t)(k0 + 3) * 128 + j];
#pragma unroll
        for (int r = 0; r < 8; ++r) {
            float4 v = *reinterpret_cast<const float4*>(&rows[r][k0]);
            acc[r] += v.x * w0 + v.y * w1 + v.z * w2 + v.w * w3;
        }
    }
#pragma unroll
    for (int r = 0; r < 8; ++r) proj[(size_t)(n0 + r) * 128 + j] = f2b(acc[r]);
}

// ---------------------------------------------------------------------------
// K6: layer-2 fused logits + online softmax + aggregate. One trace row / block.
// xr_d was pre-staged (f32) in this block's own slot of the xt output region;
// read-before-overwrite within the same block => no cross-block race.
__global__ __launch_bounds__(128) void k_fused2(
    const int* __restrict__ eadj,         // src = eadj[e2]
    const int* __restrict__ efea,
    const int* __restrict__ off, const int* __restrict__ eid,
    const __hip_bfloat16* __restrict__ xl,     // [E,128] trace@Wl2+bl2
    const __hip_bfloat16* __restrict__ proj,   // [N,128]
    const float* __restrict__ att,
    const float* __restrict__ bias,
    float* __restrict__ out)
{
    const int d = blockIdx.x;
    const int j = threadIdx.x;
    const float xr = out[XT_OFF + (size_t)d * 128 + j];  // staged xr_e row
    const float av = att[j];
    const int beg = off[d], end = off[d + 1];
    float mx = -INFINITY, den = 0.f, acc = 0.f;
    for (int i = beg; i < end; ++i) {
        const int e2 = eid[i];
        const int s = eadj[e2];
        const int nf = efea[e2];
        const float xls = b2f(xl[(size_t)s * 128 + j]);
        float m = xls + xr + b2f(proj[(size_t)nf * 128 + j]);
        m = m > 0.f ? m : 0.2f * m;
        float p = m * av;
        // butterfly sum within 32-lane head segment (C=32)
        p += __shfl_xor(p, 16, 32);
        p += __shfl_xor(p, 8, 32);
        p += __shfl_xor(p, 4, 32);
        p += __shfl_xor(p, 2, 32);
        p += __shfl_xor(p, 1, 32);
        const float mnew = fmaxf(mx, p);
        const float sc = __expf(mx - mnew);
        const float ex = __expf(p - mnew);
        den = den * sc + ex;
        acc = acc * sc + ex * xls;
        mx = mnew;
    }
    const float v = acc / (den + 1e-16f) + bias[j];
    out[XT_OFF + (size_t)d * 128 + j] = v;
}

// ---------------------------------------------------------------------------
extern "C" void kernel_launch(void* const* d_in, const int* in_sizes, int n_in,
                              void* d_out, int out_size, void* d_ws, size_t ws_size,
                              hipStream_t stream)
{
    const float* x_node   = (const float*)d_in[0];
    const float* x_trace  = (const float*)d_in[1];
    const float* x_log    = (const float*)d_in[2];
    const int*   node_adj = (const int*)d_in[3];
    const int*   edge_adj = (const int*)d_in[4];
    const int*   efea     = (const int*)d_in[5];
    const float* n2n_Wl   = (const float*)d_in[6];
    const float* n2n_bl   = (const float*)d_in[7];
    const float* n2n_Wr   = (const float*)d_in[8];
    const float* n2n_br   = (const float*)d_in[9];
    const float* n2n_We   = (const float*)d_in[10];
    const float* n2n_att  = (const float*)d_in[11];
    const float* n2n_bias = (const float*)d_in[12];
    const float* e2n_Wl   = (const float*)d_in[13];
    const float* e2n_bl   = (const float*)d_in[14];
    const float* e2n_Wr   = (const float*)d_in[15];
    const float* e2n_br   = (const float*)d_in[16];
    const float* e2n_We   = (const float*)d_in[17];
    const float* e2n_att  = (const float*)d_in[18];
    const float* e2n_bias = (const float*)d_in[19];
    float* out = (float*)d_out;

    // ---- workspace layout (~48 MB) ----
    char* w = (char*)d_ws;
    int* cnt1 = (int*)w; w += (size_t)N * 4;         // zeroed below
    int* cnt2 = (int*)w; w += (size_t)E * 4;         // zeroed below
    int* off1 = (int*)w; w += (size_t)(N + 4) * 4;
    int* cur1 = (int*)w; w += (size_t)N * 4;
    int* eid1 = (int*)w; w += (size_t)E * 4;
    int* off2 = (int*)w; w += (size_t)(E + 4) * 4;
    int* cur2 = (int*)w; w += (size_t)E * 4;
    int* eid2 = (int*)w; w += (size_t)E2 * 4;
    __hip_bfloat16* xl_n = (__hip_bfloat16*)w; w += (size_t)N * 256 * 2;
    __hip_bfloat16* xr_n = (__hip_bfloat16*)w; w += (size_t)N * 256 * 2;
    __hip_bfloat16* xl_e = (__hip_bfloat16*)w; w += (size_t)E * 128 * 2;
    __hip_bfloat16* proj = (__hip_bfloat16*)w; w += (size_t)N * 128 * 2;
    float* alpha_n = (float*)w; w += (size_t)E * 4 * 4;

    hipMemsetAsync(d_ws, 0, (size_t)(N + E) * 4, stream);

    // ---- CSR builds ----
    k_hist<<<E / 256, 256, 0, stream>>>(node_adj + E, cnt1, E);
    k_scan<<<1, 256, 0, stream>>>(cnt1, off1, cur1, N);
    k_scatter<<<E / 256, 256, 0, stream>>>(node_adj + E, cur1, eid1, E);
    k_hist<<<E2 / 256, 256, 0, stream>>>(edge_adj + E2, cnt2, E2);
    k_scan<<<1, 256, 0, stream>>>(cnt2, off2, cur2, E);
    k_scatter<<<E2 / 256, 256, 0, stream>>>(edge_adj + E2, cur2, eid2, E2);

    // ---- layer 1 ----
    k_node_gemm<<<N / 8, 256, 0, stream>>>(x_node, x_log, n2n_Wl, n2n_bl, n2n_Wr, n2n_br,
                                           xl_n, xr_n);
    k_edge_alpha1<<<E / 16, 256, 0, stream>>>(x_trace, node_adj, xl_n, xr_n,
                                              n2n_We, n2n_att, alpha_n);
    k_fused1<<<N, 256, 0, stream>>>(node_adj, off1, eid1, alpha_n, xl_n, n2n_bias, out);

    // ---- layer 2 ----
    k_proj_gemm<<<N / 8, 128, 0, stream>>>(out, e2n_We, proj);
    k_trace_gemm<<<E / 8, 128, 0, stream>>>(x_trace, e2n_Wl, e2n_bl, e2n_Wr, e2n_br,
                                            xl_e, out + XT_OFF);
    k_fused2<<<E, 128, 0, stream>>>(edge_adj, efea, off2, eid2, xl_e, proj,
                                    e2n_att, e2n_bias, out);
}

// Round 4
// 728.832 us; speedup vs baseline: 1.3745x; 1.3745x over previous
//
#include <hip/hip_runtime.h>
#include <hip/hip_bf16.h>

// Problem constants (match reference)
constexpr int N    = 8192;     // nodes
constexpr int E    = 131072;   // node-graph edges == trace rows
constexpr int E2   = 524288;   // line-graph edges

constexpr size_t XT_OFF  = (size_t)N * 128;
constexpr size_t XLG_OFF = XT_OFF + (size_t)E * 128;

typedef unsigned short u16;
typedef short s16x8 __attribute__((ext_vector_type(8)));
typedef float f32x4 __attribute__((ext_vector_type(4)));

__device__ __forceinline__ u16 f2bs(float f) {   // f32 -> bf16 bits, RNE
    unsigned x = __float_as_uint(f);
    return (u16)((x + 0x7FFF + ((x >> 16) & 1)) >> 16);
}
__device__ __forceinline__ float bs2f(u16 u) {
    return __uint_as_float((unsigned)u << 16);
}

// ---------------------------------------------------------------------------
// CSR build: histogram -> single-block chunked scan -> scatter
__global__ void k_hist(const int* __restrict__ dst, int* __restrict__ cnt, int nE)
{
    int i = blockIdx.x * 256 + threadIdx.x;
    if (i < nE) atomicAdd(&cnt[dst[i]], 1);
}

__global__ __launch_bounds__(256) void k_scan(
    const int* __restrict__ cnt, int* __restrict__ off, int* __restrict__ cur, int n)
{
    __shared__ int tile[8192];
    __shared__ int chunk[257];
    int carry = 0;
    for (int base = 0; base < n; base += 8192) {
        for (int i = threadIdx.x; i < 8192; i += 256) tile[i] = cnt[base + i];
        __syncthreads();
        const int st = threadIdx.x * 32;
        int s = 0;
        for (int k = 0; k < 32; ++k) { int v = tile[st + k]; tile[st + k] = s; s += v; }
        chunk[threadIdx.x] = s;
        __syncthreads();
        if (threadIdx.x == 0) {
            int t = 0;
            for (int c = 0; c < 256; ++c) { int v = chunk[c]; chunk[c] = t; t += v; }
            chunk[256] = t;
        }
        __syncthreads();
        const int add = carry + chunk[threadIdx.x];
        for (int k = 0; k < 32; ++k) {
            int o = add + tile[st + k];
            off[base + st + k] = o;
            cur[base + st + k] = o;
        }
        carry += chunk[256];
        __syncthreads();
    }
    if (threadIdx.x == 0) off[n] = carry;
}

__global__ void k_scatter(const int* __restrict__ dst, int* __restrict__ cur,
                          int* __restrict__ eid, int nE)
{
    int i = blockIdx.x * 256 + threadIdx.x;
    if (i < nE) {
        int pos = atomicAdd(&cur[dst[i]], 1);
        eid[pos] = i;
    }
}

// ---------------------------------------------------------------------------
// K1 (MFMA): xl_n/xr_n = concat(x_node,x_log) @ {Wl,Wr} + bias -> bf16 [N,256]
// 32 rows/block, 4 waves: w0/w1 -> Wl cols 0-127/128-255, w2/w3 -> Wr same.
__global__ __launch_bounds__(256) void k_node_gemm(
    const float* __restrict__ x_node, const float* __restrict__ x_log,
    const float* __restrict__ Wl, const float* __restrict__ bl,
    const float* __restrict__ Wr, const float* __restrict__ br,
    u16* __restrict__ xl, u16* __restrict__ xr)
{
    __shared__ u16 A[32][260];
    const int n0 = blockIdx.x * 32;
    const int tid = threadIdx.x;
    for (int i = tid; i < 32 * 256; i += 256) {
        int r = i >> 8, k = i & 255;
        float v = (k < 128) ? x_node[(size_t)(n0 + r) * 128 + k]
                            : x_log[(size_t)(n0 + r) * 128 + (k - 128)];
        A[r][k] = f2bs(v);
    }
    __syncthreads();
    const int w = tid >> 6, lane = tid & 63, lr = lane & 15, lq = lane >> 4;
    const float* W    = (w < 2) ? Wl : Wr;
    const float* bias = (w < 2) ? bl : br;
    u16* outp         = (w < 2) ? xl : xr;
    const int cb = (w & 1) * 128;
    f32x4 acc[2][8] = {};
    for (int kb = 0; kb < 8; ++kb) {
        s16x8 afr0 = *(const s16x8*)&A[lr][kb * 32 + lq * 8];
        s16x8 afr1 = *(const s16x8*)&A[16 + lr][kb * 32 + lq * 8];
#pragma unroll
        for (int ct = 0; ct < 8; ++ct) {
            const int n = cb + ct * 16 + lr;
            s16x8 bfr;
#pragma unroll
            for (int j = 0; j < 8; ++j)
                bfr[j] = (short)f2bs(W[(size_t)(kb * 32 + lq * 8 + j) * 256 + n]);
            acc[0][ct] = __builtin_amdgcn_mfma_f32_16x16x32_bf16(afr0, bfr, acc[0][ct], 0, 0, 0);
            acc[1][ct] = __builtin_amdgcn_mfma_f32_16x16x32_bf16(afr1, bfr, acc[1][ct], 0, 0, 0);
        }
    }
#pragma unroll
    for (int rt = 0; rt < 2; ++rt)
#pragma unroll
        for (int ct = 0; ct < 8; ++ct) {
            const int col = cb + ct * 16 + lr;
            const float bv = bias[col];
#pragma unroll
            for (int reg = 0; reg < 4; ++reg) {
                const int row = n0 + rt * 16 + lq * 4 + reg;
                outp[(size_t)row * 256 + col] = f2bs(acc[rt][ct][reg] + bv);
            }
        }
}

// ---------------------------------------------------------------------------
// K2 (MFMA): xl_e = trace@Wl2+bl2 (bf16) ; xr_e = trace@Wr2+br2 (f32 -> out XT)
// 32 rows/block, 4 waves: w0/w1 -> Wl cols 0-63/64-127, w2/w3 -> Wr same.
__global__ __launch_bounds__(256) void k_trace_gemm(
    const float* __restrict__ x_trace,
    const float* __restrict__ Wl, const float* __restrict__ bl,
    const float* __restrict__ Wr, const float* __restrict__ br,
    u16* __restrict__ xl, float* __restrict__ xr_out)
{
    __shared__ u16 A[32][132];
    const int e0 = blockIdx.x * 32;
    const int tid = threadIdx.x;
    for (int i = tid; i < 32 * 128; i += 256) {
        int r = i >> 7, k = i & 127;
        A[r][k] = f2bs(x_trace[(size_t)(e0 + r) * 128 + k]);
    }
    __syncthreads();
    const int w = tid >> 6, lane = tid & 63, lr = lane & 15, lq = lane >> 4;
    const float* W    = (w < 2) ? Wl : Wr;
    const float* bias = (w < 2) ? bl : br;
    const int cb = (w & 1) * 64;
    f32x4 acc[2][4] = {};
    for (int kb = 0; kb < 4; ++kb) {
        s16x8 afr0 = *(const s16x8*)&A[lr][kb * 32 + lq * 8];
        s16x8 afr1 = *(const s16x8*)&A[16 + lr][kb * 32 + lq * 8];
#pragma unroll
        for (int ct = 0; ct < 4; ++ct) {
            const int n = cb + ct * 16 + lr;
            s16x8 bfr;
#pragma unroll
            for (int j = 0; j < 8; ++j)
                bfr[j] = (short)f2bs(W[(size_t)(kb * 32 + lq * 8 + j) * 128 + n]);
            acc[0][ct] = __builtin_amdgcn_mfma_f32_16x16x32_bf16(afr0, bfr, acc[0][ct], 0, 0, 0);
            acc[1][ct] = __builtin_amdgcn_mfma_f32_16x16x32_bf16(afr1, bfr, acc[1][ct], 0, 0, 0);
        }
    }
#pragma unroll
    for (int rt = 0; rt < 2; ++rt)
#pragma unroll
        for (int ct = 0; ct < 4; ++ct) {
            const int col = cb + ct * 16 + lr;
            const float bv = bias[col];
#pragma unroll
            for (int reg = 0; reg < 4; ++reg) {
                const int row = e0 + rt * 16 + lq * 4 + reg;
                if (w < 2) xl[(size_t)row * 128 + col] = f2bs(acc[rt][ct][reg] + bv);
                else       xr_out[(size_t)row * 128 + col] = acc[rt][ct][reg] + bv;
            }
        }
}

// ---------------------------------------------------------------------------
// K3 (MFMA): fused e-GEMM (trace@We) + layer-1 logits. 32 edges/block.
// wave w == head w (cols w*64 .. w*64+63 = 4 col-tiles).
__global__ __launch_bounds__(256) void k_edge_alpha1(
    const float* __restrict__ x_trace,
    const int* __restrict__ adj,          // [2,E] src then dst
    const u16* __restrict__ xl, const u16* __restrict__ xr,   // [N,256] bf16
    const float* __restrict__ We, const float* __restrict__ att,
    float* __restrict__ alpha)
{
    __shared__ u16 A[32][132];
    __shared__ int ss[32], dd[32];
    const int e0 = blockIdx.x * 32;
    const int tid = threadIdx.x;
    for (int i = tid; i < 32 * 128; i += 256) {
        int r = i >> 7, k = i & 127;
        A[r][k] = f2bs(x_trace[(size_t)(e0 + r) * 128 + k]);
    }
    if (tid < 32) { ss[tid] = adj[e0 + tid]; dd[tid] = adj[E + e0 + tid]; }
    __syncthreads();
    const int w = tid >> 6, lane = tid & 63, lr = lane & 15, lq = lane >> 4;
    f32x4 acc[2][4] = {};
    for (int kb = 0; kb < 4; ++kb) {
        s16x8 afr0 = *(const s16x8*)&A[lr][kb * 32 + lq * 8];
        s16x8 afr1 = *(const s16x8*)&A[16 + lr][kb * 32 + lq * 8];
#pragma unroll
        for (int ct = 0; ct < 4; ++ct) {
            const int n = w * 64 + ct * 16 + lr;
            s16x8 bfr;
#pragma unroll
            for (int j = 0; j < 8; ++j)
                bfr[j] = (short)f2bs(We[(size_t)(kb * 32 + lq * 8 + j) * 256 + n]);
            acc[0][ct] = __builtin_amdgcn_mfma_f32_16x16x32_bf16(afr0, bfr, acc[0][ct], 0, 0, 0);
            acc[1][ct] = __builtin_amdgcn_mfma_f32_16x16x32_bf16(afr1, bfr, acc[1][ct], 0, 0, 0);
        }
    }
    // epilogue: m = e + xl[s] + xr[d]; leaky; dot with att; reduce over head cols
    float attv[4];
#pragma unroll
    for (int ct = 0; ct < 4; ++ct) attv[ct] = att[w * 64 + ct * 16 + lr];
    float sums[2][4] = {};
#pragma unroll
    for (int rt = 0; rt < 2; ++rt)
#pragma unroll
        for (int reg = 0; reg < 4; ++reg) {
            const int rowt = rt * 16 + lq * 4 + reg;
            const int s = ss[rowt], d = dd[rowt];
            float acc_s = 0.f;
#pragma unroll
            for (int ct = 0; ct < 4; ++ct) {
                const int col = w * 64 + ct * 16 + lr;
                float m = acc[rt][ct][reg]
                        + bs2f(xl[(size_t)s * 256 + col])
                        + bs2f(xr[(size_t)d * 256 + col]);
                m = m > 0.f ? m : 0.2f * m;
                acc_s += m * attv[ct];
            }
            sums[rt][reg] = acc_s;
        }
#pragma unroll
    for (int rt = 0; rt < 2; ++rt)
#pragma unroll
        for (int reg = 0; reg < 4; ++reg) {
            float p = sums[rt][reg];
            p += __shfl_xor(p, 8);
            p += __shfl_xor(p, 4);
            p += __shfl_xor(p, 2);
            p += __shfl_xor(p, 1);
            if (lr == 0)
                alpha[(size_t)(e0 + rt * 16 + lq * 4 + reg) * 4 + w] = p;
        }
}

// ---------------------------------------------------------------------------
// K4: layer-1 fused online-softmax + gather-aggregate. One node per block.
__global__ __launch_bounds__(256) void k_fused1(
    const int* __restrict__ adj,
    const int* __restrict__ off, const int* __restrict__ eid,
    const float* __restrict__ alpha,
    const u16* __restrict__ xl,
    const float* __restrict__ bias,
    float* __restrict__ out)
{
    const int n = blockIdx.x;
    const int j = threadIdx.x;
    const int h = j >> 6;
    const int beg = off[n], end = off[n + 1];
    float mx = -INFINITY, den = 0.f, acc = 0.f;
    for (int i = beg; i < end; ++i) {
        const int e = eid[i];
        const int s = adj[e];
        const float pe = alpha[(size_t)e * 4 + h];
        const float mnew = fmaxf(mx, pe);
        const float sc = __expf(mx - mnew);
        const float ex = __expf(pe - mnew);
        const float feat = bs2f(xl[(size_t)s * 256 + j]);
        den = den * sc + ex;
        acc = acc * sc + ex * feat;
        mx = mnew;
    }
    const float v = acc / (den + 1e-16f) + bias[j];
    if (j < 128) out[(size_t)n * 128 + j] = v;
    else         out[XLG_OFF + (size_t)n * 128 + (j - 128)] = v;
}

// ---------------------------------------------------------------------------
// K5: proj = node_out @ e2n_We  [N,128] bf16
__global__ __launch_bounds__(128) void k_proj_gemm(
    const float* __restrict__ out_node, const float* __restrict__ We,
    u16* __restrict__ proj)
{
    __shared__ float rows[8][256];
    const int n0 = blockIdx.x * 8;
    const int tid = threadIdx.x;
    for (int i = tid; i < 8 * 256; i += 128) {
        int r = i >> 8, k = i & 255;
        float v = (k < 128) ? out_node[(size_t)(n0 + r) * 128 + k]
                            : out_node[XLG_OFF + (size_t)(n0 + r) * 128 + (k - 128)];
        rows[r][k] = v;
    }
    __syncthreads();
    const int j = tid;
    float acc[8];
#pragma unroll
    for (int r = 0; r < 8; ++r) acc[r] = 0.f;
    for (int k0 = 0; k0 < 256; k0 += 4) {
        float w0 = We[(size_t)(k0 + 0) * 128 + j];
        float w1 = We[(size_t)(k0 + 1) * 128 + j];
        float w2 = We[(size_t)(k0 + 2) * 128 + j];
        float w3 = We[(size_t)(k0 + 3) * 128 + j];
#pragma unroll
        for (int r = 0; r < 8; ++r) {
            float4 v = *reinterpret_cast<const float4*>(&rows[r][k0]);
            acc[r] += v.x * w0 + v.y * w1 + v.z * w2 + v.w * w3;
        }
    }
#pragma unroll
    for (int r = 0; r < 8; ++r) proj[(size_t)(n0 + r) * 128 + j] = f2bs(acc[r]);
}

// ---------------------------------------------------------------------------
// K6: layer-2 fused logits + online softmax + aggregate. 2 trace rows / block.
// xr_d pre-staged (f32) in this row's slot of the xt output region.
__global__ __launch_bounds__(256) void k_fused2(
    const int* __restrict__ eadj,
    const int* __restrict__ efea,
    const int* __restrict__ off, const int* __restrict__ eid,
    const u16* __restrict__ xl,        // [E,128] trace@Wl2+bl2 bf16
    const u16* __restrict__ proj,      // [N,128] bf16
    const float* __restrict__ att,
    const float* __restrict__ bias,
    float* __restrict__ out)
{
    const int d = blockIdx.x * 2 + (threadIdx.x >> 7);
    const int j = threadIdx.x & 127;
    const float xr = out[XT_OFF + (size_t)d * 128 + j];
    const float av = att[j];
    const int beg = off[d], end = off[d + 1];
    float mx = -INFINITY, den = 0.f, acc = 0.f;
    for (int i = beg; i < end; ++i) {
        const int e2 = eid[i];
        const int s = eadj[e2];
        const int nf = efea[e2];
        const float xls = bs2f(xl[(size_t)s * 128 + j]);
        float m = xls + xr + bs2f(proj[(size_t)nf * 128 + j]);
        m = m > 0.f ? m : 0.2f * m;
        float p = m * av;
        p += __shfl_xor(p, 16, 32);
        p += __shfl_xor(p, 8, 32);
        p += __shfl_xor(p, 4, 32);
        p += __shfl_xor(p, 2, 32);
        p += __shfl_xor(p, 1, 32);
        const float mnew = fmaxf(mx, p);
        const float sc = __expf(mx - mnew);
        const float ex = __expf(p - mnew);
        den = den * sc + ex;
        acc = acc * sc + ex * xls;
        mx = mnew;
    }
    const float v = acc / (den + 1e-16f) + bias[j];
    out[XT_OFF + (size_t)d * 128 + j] = v;
}

// ---------------------------------------------------------------------------
extern "C" void kernel_launch(void* const* d_in, const int* in_sizes, int n_in,
                              void* d_out, int out_size, void* d_ws, size_t ws_size,
                              hipStream_t stream)
{
    const float* x_node   = (const float*)d_in[0];
    const float* x_trace  = (const float*)d_in[1];
    const float* x_log    = (const float*)d_in[2];
    const int*   node_adj = (const int*)d_in[3];
    const int*   edge_adj = (const int*)d_in[4];
    const int*   efea     = (const int*)d_in[5];
    const float* n2n_Wl   = (const float*)d_in[6];
    const float* n2n_bl   = (const float*)d_in[7];
    const float* n2n_Wr   = (const float*)d_in[8];
    const float* n2n_br   = (const float*)d_in[9];
    const float* n2n_We   = (const float*)d_in[10];
    const float* n2n_att  = (const float*)d_in[11];
    const float* n2n_bias = (const float*)d_in[12];
    const float* e2n_Wl   = (const float*)d_in[13];
    const float* e2n_bl   = (const float*)d_in[14];
    const float* e2n_Wr   = (const float*)d_in[15];
    const float* e2n_br   = (const float*)d_in[16];
    const float* e2n_We   = (const float*)d_in[17];
    const float* e2n_att  = (const float*)d_in[18];
    const float* e2n_bias = (const float*)d_in[19];
    float* out = (float*)d_out;

    // ---- workspace layout (~48 MB) ----
    char* w = (char*)d_ws;
    int* cnt1 = (int*)w; w += (size_t)N * 4;         // zeroed below
    int* cnt2 = (int*)w; w += (size_t)E * 4;         // zeroed below
    int* off1 = (int*)w; w += (size_t)(N + 4) * 4;
    int* cur1 = (int*)w; w += (size_t)N * 4;
    int* eid1 = (int*)w; w += (size_t)E * 4;
    int* off2 = (int*)w; w += (size_t)(E + 4) * 4;
    int* cur2 = (int*)w; w += (size_t)E * 4;
    int* eid2 = (int*)w; w += (size_t)E2 * 4;
    u16* xl_n = (u16*)w; w += (size_t)N * 256 * 2;
    u16* xr_n = (u16*)w; w += (size_t)N * 256 * 2;
    u16* xl_e = (u16*)w; w += (size_t)E * 128 * 2;
    u16* proj = (u16*)w; w += (size_t)N * 128 * 2;
    float* alpha_n = (float*)w; w += (size_t)E * 4 * 4;

    hipMemsetAsync(d_ws, 0, (size_t)(N + E) * 4, stream);

    // ---- CSR builds ----
    k_hist<<<E / 256, 256, 0, stream>>>(node_adj + E, cnt1, E);
    k_scan<<<1, 256, 0, stream>>>(cnt1, off1, cur1, N);
    k_scatter<<<E / 256, 256, 0, stream>>>(node_adj + E, cur1, eid1, E);
    k_hist<<<E2 / 256, 256, 0, stream>>>(edge_adj + E2, cnt2, E2);
    k_scan<<<1, 256, 0, stream>>>(cnt2, off2, cur2, E);
    k_scatter<<<E2 / 256, 256, 0, stream>>>(edge_adj + E2, cur2, eid2, E2);

    // ---- layer 1 ----
    k_node_gemm<<<N / 32, 256, 0, stream>>>(x_node, x_log, n2n_Wl, n2n_bl, n2n_Wr, n2n_br,
                                            xl_n, xr_n);
    k_edge_alpha1<<<E / 32, 256, 0, stream>>>(x_trace, node_adj, xl_n, xr_n,
                                              n2n_We, n2n_att, alpha_n);
    k_fused1<<<N, 256, 0, stream>>>(node_adj, off1, eid1, alpha_n, xl_n, n2n_bias, out);

    // ---- layer 2 ----
    k_proj_gemm<<<N / 8, 128, 0, stream>>>(out, e2n_We, proj);
    k_trace_gemm<<<E / 32, 256, 0, stream>>>(x_trace, e2n_Wl, e2n_bl, e2n_Wr, e2n_br,
                                             xl_e, out + XT_OFF);
    k_fused2<<<E / 2, 256, 0, stream>>>(edge_adj, efea, off2, eid2, xl_e, proj,
                                        e2n_att, e2n_bias, out);
}

// Round 5
// 554.603 us; speedup vs baseline: 1.8063x; 1.3142x over previous
//
#include <hip/hip_runtime.h>
#include <hip/hip_bf16.h>

// Problem constants (match reference)
constexpr int N    = 8192;     // nodes
constexpr int E    = 131072;   // node-graph edges == trace rows
constexpr int E2   = 524288;   // line-graph edges

constexpr size_t XT_OFF  = (size_t)N * 128;
constexpr size_t XLG_OFF = XT_OFF + (size_t)E * 128;

typedef unsigned short u16;
typedef short s16x8 __attribute__((ext_vector_type(8)));
typedef float f32x4 __attribute__((ext_vector_type(4)));

__device__ __forceinline__ u16 f2bs(float f) {   // f32 -> bf16 bits, RNE
    unsigned x = __float_as_uint(f);
    return (u16)((x + 0x7FFF + ((x >> 16) & 1)) >> 16);
}
__device__ __forceinline__ float bs2f(u16 u) {
    return __uint_as_float((unsigned)u << 16);
}

// ---------------------------------------------------------------------------
// K0: weight pre-transpose f32 [K,N] -> bf16 [N,K] (one launch, all 6 mats)
__global__ __launch_bounds__(256) void k_prep(
    const float* __restrict__ Wl, const float* __restrict__ Wr,
    const float* __restrict__ We, const float* __restrict__ Wl2,
    const float* __restrict__ Wr2, const float* __restrict__ We2,
    u16* __restrict__ Wlt, u16* __restrict__ Wrt, u16* __restrict__ Wet,
    u16* __restrict__ Wl2t, u16* __restrict__ Wr2t, u16* __restrict__ We2t)
{
    const int gid = blockIdx.x * 256 + threadIdx.x;
    const float* src; u16* dst; int base, Kk, sh;
    if      (gid <  65536) { src = Wl;  dst = Wlt;  base = 0;      Kk = 256; sh = 8; }
    else if (gid < 131072) { src = Wr;  dst = Wrt;  base = 65536;  Kk = 256; sh = 8; }
    else if (gid < 163840) { src = We;  dst = Wet;  base = 131072; Kk = 128; sh = 8; }
    else if (gid < 180224) { src = Wl2; dst = Wl2t; base = 163840; Kk = 128; sh = 7; }
    else if (gid < 196608) { src = Wr2; dst = Wr2t; base = 180224; Kk = 128; sh = 7; }
    else                   { src = We2; dst = We2t; base = 196608; Kk = 256; sh = 7; }
    const int l = gid - base;
    const int k = l >> sh, nn = l & ((1 << sh) - 1);
    dst[(size_t)nn * Kk + k] = f2bs(src[l]);
}

// ---------------------------------------------------------------------------
// CSR build: histogram -> single-block scan (shfl) -> scatter
__global__ void k_hist(const int* __restrict__ dst, int* __restrict__ cnt, int nE)
{
    int i = blockIdx.x * 256 + threadIdx.x;
    if (i < nE) atomicAdd(&cnt[dst[i]], 1);
}

__global__ __launch_bounds__(256) void k_scan(
    const int* __restrict__ cnt, int* __restrict__ off, int* __restrict__ cur, int n)
{
    __shared__ int tile[8192];
    __shared__ int wsum[4];
    const int tid = threadIdx.x, lane = tid & 63, wv = tid >> 6;
    int carry = 0;
    for (int base = 0; base < n; base += 8192) {
        for (int i = tid; i < 8192; i += 256) tile[i] = cnt[base + i];
        __syncthreads();
        const int st = tid * 32;
        int s = 0;
        for (int k = 0; k < 32; ++k) { int v = tile[st + k]; tile[st + k] = s; s += v; }
        const int tsum = s;
        int incl = s;
        for (int o = 1; o < 64; o <<= 1) {
            int v = __shfl_up(incl, o);
            if (lane >= o) incl += v;
        }
        if (lane == 63) wsum[wv] = incl;
        __syncthreads();
        int woff = 0;
        for (int wq = 0; wq < wv; ++wq) woff += wsum[wq];
        const int tot = wsum[0] + wsum[1] + wsum[2] + wsum[3];
        const int add = carry + woff + incl - tsum;
        for (int k = 0; k < 32; ++k) {
            int o2 = add + tile[st + k];
            off[base + st + k] = o2;
            cur[base + st + k] = o2;
        }
        carry += tot;
        __syncthreads();
    }
    if (tid == 0) off[n] = carry;
}

__global__ void k_scatter(const int* __restrict__ dst, int* __restrict__ cur,
                          int* __restrict__ eid, int nE)
{
    int i = blockIdx.x * 256 + threadIdx.x;
    if (i < nE) {
        int pos = atomicAdd(&cur[dst[i]], 1);
        eid[pos] = i;
    }
}

// ---------------------------------------------------------------------------
// K1 (MFMA): xl_n/xr_n = concat(x_node,x_log) @ {Wl,Wr} + bias -> bf16 [N,256]
__global__ __launch_bounds__(256) void k_node_gemm(
    const float* __restrict__ x_node, const float* __restrict__ x_log,
    const u16* __restrict__ Wlt, const float* __restrict__ bl,
    const u16* __restrict__ Wrt, const float* __restrict__ br,
    u16* __restrict__ xl, u16* __restrict__ xr)
{
    __shared__ u16 A[32][260];
    const int n0 = blockIdx.x * 32;
    const int tid = threadIdx.x;
    for (int i = tid; i < 32 * 256; i += 256) {
        int r = i >> 8, k = i & 255;
        float v = (k < 128) ? x_node[(size_t)(n0 + r) * 128 + k]
                            : x_log[(size_t)(n0 + r) * 128 + (k - 128)];
        A[r][k] = f2bs(v);
    }
    __syncthreads();
    const int w = tid >> 6, lane = tid & 63, lr = lane & 15, lq = lane >> 4;
    const u16* Wt     = (w < 2) ? Wlt : Wrt;
    const float* bias = (w < 2) ? bl : br;
    u16* outp         = (w < 2) ? xl : xr;
    const int cb = (w & 1) * 128;
    f32x4 acc[2][8] = {};
    for (int kb = 0; kb < 8; ++kb) {
        s16x8 afr0 = *(const s16x8*)&A[lr][kb * 32 + lq * 8];
        s16x8 afr1 = *(const s16x8*)&A[16 + lr][kb * 32 + lq * 8];
#pragma unroll
        for (int ct = 0; ct < 8; ++ct) {
            const int n = cb + ct * 16 + lr;
            s16x8 bfr = *(const s16x8*)&Wt[(size_t)n * 256 + kb * 32 + lq * 8];
            acc[0][ct] = __builtin_amdgcn_mfma_f32_16x16x32_bf16(afr0, bfr, acc[0][ct], 0, 0, 0);
            acc[1][ct] = __builtin_amdgcn_mfma_f32_16x16x32_bf16(afr1, bfr, acc[1][ct], 0, 0, 0);
        }
    }
#pragma unroll
    for (int rt = 0; rt < 2; ++rt)
#pragma unroll
        for (int ct = 0; ct < 8; ++ct) {
            const int col = cb + ct * 16 + lr;
            const float bv = bias[col];
#pragma unroll
            for (int reg = 0; reg < 4; ++reg) {
                const int row = n0 + rt * 16 + lq * 4 + reg;
                outp[(size_t)row * 256 + col] = f2bs(acc[rt][ct][reg] + bv);
            }
        }
}

// ---------------------------------------------------------------------------
// K2 (MFMA): xl_e = trace@Wl2+bl2 (bf16) ; xr_e = trace@Wr2+br2 (f32 -> out XT)
__global__ __launch_bounds__(256) void k_trace_gemm(
    const float* __restrict__ x_trace,
    const u16* __restrict__ Wl2t, const float* __restrict__ bl,
    const u16* __restrict__ Wr2t, const float* __restrict__ br,
    u16* __restrict__ xl, float* __restrict__ xr_out)
{
    __shared__ u16 A[32][132];
    const int e0 = blockIdx.x * 32;
    const int tid = threadIdx.x;
    for (int i = tid; i < 32 * 128; i += 256) {
        int r = i >> 7, k = i & 127;
        A[r][k] = f2bs(x_trace[(size_t)(e0 + r) * 128 + k]);
    }
    __syncthreads();
    const int w = tid >> 6, lane = tid & 63, lr = lane & 15, lq = lane >> 4;
    const u16* Wt     = (w < 2) ? Wl2t : Wr2t;
    const float* bias = (w < 2) ? bl : br;
    const int cb = (w & 1) * 64;
    f32x4 acc[2][4] = {};
    for (int kb = 0; kb < 4; ++kb) {
        s16x8 afr0 = *(const s16x8*)&A[lr][kb * 32 + lq * 8];
        s16x8 afr1 = *(const s16x8*)&A[16 + lr][kb * 32 + lq * 8];
#pragma unroll
        for (int ct = 0; ct < 4; ++ct) {
            const int n = cb + ct * 16 + lr;
            s16x8 bfr = *(const s16x8*)&Wt[(size_t)n * 128 + kb * 32 + lq * 8];
            acc[0][ct] = __builtin_amdgcn_mfma_f32_16x16x32_bf16(afr0, bfr, acc[0][ct], 0, 0, 0);
            acc[1][ct] = __builtin_amdgcn_mfma_f32_16x16x32_bf16(afr1, bfr, acc[1][ct], 0, 0, 0);
        }
    }
#pragma unroll
    for (int rt = 0; rt < 2; ++rt)
#pragma unroll
        for (int ct = 0; ct < 4; ++ct) {
            const int col = cb + ct * 16 + lr;
            const float bv = bias[col];
#pragma unroll
            for (int reg = 0; reg < 4; ++reg) {
                const int row = e0 + rt * 16 + lq * 4 + reg;
                if (w < 2) xl[(size_t)row * 128 + col] = f2bs(acc[rt][ct][reg] + bv);
                else       xr_out[(size_t)row * 128 + col] = acc[rt][ct][reg] + bv;
            }
        }
}

// ---------------------------------------------------------------------------
// K3 (MFMA): fused e-GEMM (trace@We) + layer-1 logits. 32 edges/block.
__global__ __launch_bounds__(256) void k_edge_alpha1(
    const float* __restrict__ x_trace,
    const int* __restrict__ adj,          // [2,E] src then dst
    const u16* __restrict__ xl, const u16* __restrict__ xr,   // [N,256] bf16
    const u16* __restrict__ Wet, const float* __restrict__ att,
    float* __restrict__ alpha)
{
    __shared__ u16 A[32][132];
    __shared__ int ss[32], dd[32];
    const int e0 = blockIdx.x * 32;
    const int tid = threadIdx.x;
    for (int i = tid; i < 32 * 128; i += 256) {
        int r = i >> 7, k = i & 127;
        A[r][k] = f2bs(x_trace[(size_t)(e0 + r) * 128 + k]);
    }
    if (tid < 32) { ss[tid] = adj[e0 + tid]; dd[tid] = adj[E + e0 + tid]; }
    __syncthreads();
    const int w = tid >> 6, lane = tid & 63, lr = lane & 15, lq = lane >> 4;
    f32x4 acc[2][4] = {};
    for (int kb = 0; kb < 4; ++kb) {
        s16x8 afr0 = *(const s16x8*)&A[lr][kb * 32 + lq * 8];
        s16x8 afr1 = *(const s16x8*)&A[16 + lr][kb * 32 + lq * 8];
#pragma unroll
        for (int ct = 0; ct < 4; ++ct) {
            const int n = w * 64 + ct * 16 + lr;
            s16x8 bfr = *(const s16x8*)&Wet[(size_t)n * 128 + kb * 32 + lq * 8];
            acc[0][ct] = __builtin_amdgcn_mfma_f32_16x16x32_bf16(afr0, bfr, acc[0][ct], 0, 0, 0);
            acc[1][ct] = __builtin_amdgcn_mfma_f32_16x16x32_bf16(afr1, bfr, acc[1][ct], 0, 0, 0);
        }
    }
    float attv[4];
#pragma unroll
    for (int ct = 0; ct < 4; ++ct) attv[ct] = att[w * 64 + ct * 16 + lr];
    float sums[2][4] = {};
#pragma unroll
    for (int rt = 0; rt < 2; ++rt)
#pragma unroll
        for (int reg = 0; reg < 4; ++reg) {
            const int rowt = rt * 16 + lq * 4 + reg;
            const int s = ss[rowt], d = dd[rowt];
            float acc_s = 0.f;
#pragma unroll
            for (int ct = 0; ct < 4; ++ct) {
                const int col = w * 64 + ct * 16 + lr;
                float m = acc[rt][ct][reg]
                        + bs2f(xl[(size_t)s * 256 + col])
                        + bs2f(xr[(size_t)d * 256 + col]);
                m = m > 0.f ? m : 0.2f * m;
                acc_s += m * attv[ct];
            }
            sums[rt][reg] = acc_s;
        }
#pragma unroll
    for (int rt = 0; rt < 2; ++rt)
#pragma unroll
        for (int reg = 0; reg < 4; ++reg) {
            float p = sums[rt][reg];
            p += __shfl_xor(p, 8);
            p += __shfl_xor(p, 4);
            p += __shfl_xor(p, 2);
            p += __shfl_xor(p, 1);
            if (lr == 0)
                alpha[(size_t)(e0 + rt * 16 + lq * 4 + reg) * 4 + w] = p;
        }
}

// ---------------------------------------------------------------------------
// K4: layer-1 online-softmax + gather. One node per WAVE, 4 dims/lane, batch-4.
__global__ __launch_bounds__(256) void k_fused1(
    const int* __restrict__ adj,
    const int* __restrict__ off, const int* __restrict__ eid,
    const float* __restrict__ alpha,
    const u16* __restrict__ xl,
    const float* __restrict__ bias,
    float* __restrict__ out)
{
    const int wv = __builtin_amdgcn_readfirstlane(threadIdx.x >> 6);
    const int lane = threadIdx.x & 63;
    const int n = blockIdx.x * 4 + wv;
    const int c = lane * 4;            // dims c..c+3
    const int h = lane >> 4;           // head (64 dims / head, 16 lanes / head)
    const int beg = off[n], end = off[n + 1];
    float mx = -INFINITY, den = 0.f;
    float a0 = 0.f, a1 = 0.f, a2 = 0.f, a3 = 0.f;
    int i = beg;
    while (i + 4 <= end) {
        int ea[4], sa[4];
#pragma unroll
        for (int k = 0; k < 4; ++k) ea[k] = eid[i + k];
#pragma unroll
        for (int k = 0; k < 4; ++k) sa[k] = adj[ea[k]];
        float pe[4]; ushort4 xv[4];
#pragma unroll
        for (int k = 0; k < 4; ++k) {
            pe[k] = alpha[(size_t)ea[k] * 4 + h];
            xv[k] = *(const ushort4*)&xl[(size_t)sa[k] * 256 + c];
        }
#pragma unroll
        for (int k = 0; k < 4; ++k) {
            const float mnew = fmaxf(mx, pe[k]);
            const float sc = __expf(mx - mnew);
            const float ex = __expf(pe[k] - mnew);
            den = den * sc + ex;
            a0 = a0 * sc + ex * bs2f(xv[k].x);
            a1 = a1 * sc + ex * bs2f(xv[k].y);
            a2 = a2 * sc + ex * bs2f(xv[k].z);
            a3 = a3 * sc + ex * bs2f(xv[k].w);
            mx = mnew;
        }
        i += 4;
    }
    for (; i < end; ++i) {
        const int e = eid[i];
        const int s = adj[e];
        const float pe = alpha[(size_t)e * 4 + h];
        const ushort4 xv = *(const ushort4*)&xl[(size_t)s * 256 + c];
        const float mnew = fmaxf(mx, pe);
        const float sc = __expf(mx - mnew);
        const float ex = __expf(pe - mnew);
        den = den * sc + ex;
        a0 = a0 * sc + ex * bs2f(xv.x);
        a1 = a1 * sc + ex * bs2f(xv.y);
        a2 = a2 * sc + ex * bs2f(xv.z);
        a3 = a3 * sc + ex * bs2f(xv.w);
        mx = mnew;
    }
    const float inv = 1.f / (den + 1e-16f);
    float4 r;
    r.x = a0 * inv + bias[c + 0];
    r.y = a1 * inv + bias[c + 1];
    r.z = a2 * inv + bias[c + 2];
    r.w = a3 * inv + bias[c + 3];
    if (lane < 32) *(float4*)&out[(size_t)n * 128 + c] = r;
    else           *(float4*)&out[XLG_OFF + (size_t)n * 128 + (c - 128)] = r;
}

// ---------------------------------------------------------------------------
// K5 (MFMA): proj = node_out @ e2n_We  [N,128] bf16
__global__ __launch_bounds__(256) void k_proj_gemm(
    const float* __restrict__ out_node, const u16* __restrict__ We2t,  // [128][256]
    u16* __restrict__ proj)
{
    __shared__ u16 A[32][260];
    const int n0 = blockIdx.x * 32;
    const int tid = threadIdx.x;
    for (int i = tid; i < 32 * 256; i += 256) {
        int r = i >> 8, k = i & 255;
        float v = (k < 128) ? out_node[(size_t)(n0 + r) * 128 + k]
                            : out_node[XLG_OFF + (size_t)(n0 + r) * 128 + (k - 128)];
        A[r][k] = f2bs(v);
    }
    __syncthreads();
    const int w = tid >> 6, lane = tid & 63, lr = lane & 15, lq = lane >> 4;
    f32x4 acc[2][2] = {};
    for (int kb = 0; kb < 8; ++kb) {
        s16x8 afr0 = *(const s16x8*)&A[lr][kb * 32 + lq * 8];
        s16x8 afr1 = *(const s16x8*)&A[16 + lr][kb * 32 + lq * 8];
#pragma unroll
        for (int ct = 0; ct < 2; ++ct) {
            const int col = w * 32 + ct * 16 + lr;
            s16x8 bfr = *(const s16x8*)&We2t[(size_t)col * 256 + kb * 32 + lq * 8];
            acc[0][ct] = __builtin_amdgcn_mfma_f32_16x16x32_bf16(afr0, bfr, acc[0][ct], 0, 0, 0);
            acc[1][ct] = __builtin_amdgcn_mfma_f32_16x16x32_bf16(afr1, bfr, acc[1][ct], 0, 0, 0);
        }
    }
#pragma unroll
    for (int rt = 0; rt < 2; ++rt)
#pragma unroll
        for (int ct = 0; ct < 2; ++ct) {
            const int col = w * 32 + ct * 16 + lr;
#pragma unroll
            for (int reg = 0; reg < 4; ++reg) {
                const int row = n0 + rt * 16 + lq * 4 + reg;
                proj[(size_t)row * 128 + col] = f2bs(acc[rt][ct][reg]);
            }
        }
}

// ---------------------------------------------------------------------------
// K6: layer-2 fused logits + online softmax + aggregate. One row per WAVE,
// 2 dims/lane, batch-4 software pipeline. xr_d staged f32 in own out-XT slot.
__global__ __launch_bounds__(256) void k_fused2(
    const int* __restrict__ eadj,
    const int* __restrict__ efea,
    const int* __restrict__ off, const int* __restrict__ eid,
    const u16* __restrict__ xl,        // [E,128] trace@Wl2+bl2 bf16
    const u16* __restrict__ proj,      // [N,128] bf16
    const float* __restrict__ att,
    const float* __restrict__ bias,
    float* __restrict__ out)
{
    const int wv = __builtin_amdgcn_readfirstlane(threadIdx.x >> 6);
    const int lane = threadIdx.x & 63;
    const int d = blockIdx.x * 4 + wv;
    const int c = lane * 2;            // dims c, c+1 (head = lane>>4, 16 lanes/head)
    const float2 xr2 = *(const float2*)&out[XT_OFF + (size_t)d * 128 + c];
    const float xr0 = xr2.x, xr1 = xr2.y;
    const float av0 = att[c], av1 = att[c + 1];
    const int beg = off[d], end = off[d + 1];
    float mx = -INFINITY, den = 0.f, a0 = 0.f, a1 = 0.f;
    int i = beg;
    while (i + 4 <= end) {
        int e2a[4], sa[4], nfa[4];
#pragma unroll
        for (int k = 0; k < 4; ++k) e2a[k] = eid[i + k];
#pragma unroll
        for (int k = 0; k < 4; ++k) { sa[k] = eadj[e2a[k]]; nfa[k] = efea[e2a[k]]; }
        unsigned xv[4], pv[4];
#pragma unroll
        for (int k = 0; k < 4; ++k) {
            xv[k] = *(const unsigned*)&xl[(size_t)sa[k] * 128 + c];
            pv[k] = *(const unsigned*)&proj[(size_t)nfa[k] * 128 + c];
        }
        float p[4], x0[4], x1[4];
#pragma unroll
        for (int k = 0; k < 4; ++k) {
            x0[k] = bs2f((u16)(xv[k] & 0xffff));
            x1[k] = bs2f((u16)(xv[k] >> 16));
            float m0 = x0[k] + xr0 + bs2f((u16)(pv[k] & 0xffff));
            float m1 = x1[k] + xr1 + bs2f((u16)(pv[k] >> 16));
            m0 = m0 > 0.f ? m0 : 0.2f * m0;
            m1 = m1 > 0.f ? m1 : 0.2f * m1;
            float pp = m0 * av0 + m1 * av1;
            pp += __shfl_xor(pp, 8, 16);
            pp += __shfl_xor(pp, 4, 16);
            pp += __shfl_xor(pp, 2, 16);
            pp += __shfl_xor(pp, 1, 16);
            p[k] = pp;
        }
#pragma unroll
        for (int k = 0; k < 4; ++k) {
            const float mnew = fmaxf(mx, p[k]);
            const float sc = __expf(mx - mnew);
            const float ex = __expf(p[k] - mnew);
            den = den * sc + ex;
            a0 = a0 * sc + ex * x0[k];
            a1 = a1 * sc + ex * x1[k];
            mx = mnew;
        }
        i += 4;
    }
    for (; i < end; ++i) {
        const int e2 = eid[i];
        const int s = eadj[e2], nf = efea[e2];
        const unsigned xv = *(const unsigned*)&xl[(size_t)s * 128 + c];
        const unsigned pv = *(const unsigned*)&proj[(size_t)nf * 128 + c];
        const float x0 = bs2f((u16)(xv & 0xffff));
        const float x1 = bs2f((u16)(xv >> 16));
        float m0 = x0 + xr0 + bs2f((u16)(pv & 0xffff));
        float m1 = x1 + xr1 + bs2f((u16)(pv >> 16));
        m0 = m0 > 0.f ? m0 : 0.2f * m0;
        m1 = m1 > 0.f ? m1 : 0.2f * m1;
        float pp = m0 * av0 + m1 * av1;
        pp += __shfl_xor(pp, 8, 16);
        pp += __shfl_xor(pp, 4, 16);
        pp += __shfl_xor(pp, 2, 16);
        pp += __shfl_xor(pp, 1, 16);
        const float mnew = fmaxf(mx, pp);
        const float sc = __expf(mx - mnew);
        const float ex = __expf(pp - mnew);
        den = den * sc + ex;
        a0 = a0 * sc + ex * x0;
        a1 = a1 * sc + ex * x1;
        mx = mnew;
    }
    const float inv = 1.f / (den + 1e-16f);
    float2 o2;
    o2.x = a0 * inv + bias[c];
    o2.y = a1 * inv + bias[c + 1];
    *(float2*)&out[XT_OFF + (size_t)d * 128 + c] = o2;
}

// ---------------------------------------------------------------------------
extern "C" void kernel_launch(void* const* d_in, const int* in_sizes, int n_in,
                              void* d_out, int out_size, void* d_ws, size_t ws_size,
                              hipStream_t stream)
{
    const float* x_node   = (const float*)d_in[0];
    const float* x_trace  = (const float*)d_in[1];
    const float* x_log    = (const float*)d_in[2];
    const int*   node_adj = (const int*)d_in[3];
    const int*   edge_adj = (const int*)d_in[4];
    const int*   efea     = (const int*)d_in[5];
    const float* n2n_Wl   = (const float*)d_in[6];
    const float* n2n_bl   = (const float*)d_in[7];
    const float* n2n_Wr   = (const float*)d_in[8];
    const float* n2n_br   = (const float*)d_in[9];
    const float* n2n_We   = (const float*)d_in[10];
    const float* n2n_att  = (const float*)d_in[11];
    const float* n2n_bias = (const float*)d_in[12];
    const float* e2n_Wl   = (const float*)d_in[13];
    const float* e2n_bl   = (const float*)d_in[14];
    const float* e2n_Wr   = (const float*)d_in[15];
    const float* e2n_br   = (const float*)d_in[16];
    const float* e2n_We   = (const float*)d_in[17];
    const float* e2n_att  = (const float*)d_in[18];
    const float* e2n_bias = (const float*)d_in[19];
    float* out = (float*)d_out;

    // ---- workspace layout (~48.7 MB) ----
    char* w = (char*)d_ws;
    int* cnt1 = (int*)w; w += (size_t)N * 4;         // zeroed below
    int* cnt2 = (int*)w; w += (size_t)E * 4;         // zeroed below
    int* off1 = (int*)w; w += (size_t)(N + 4) * 4;
    int* cur1 = (int*)w; w += (size_t)N * 4;
    int* eid1 = (int*)w; w += (size_t)E * 4;
    int* off2 = (int*)w; w += (size_t)(E + 4) * 4;
    int* cur2 = (int*)w; w += (size_t)E * 4;
    int* eid2 = (int*)w; w += (size_t)E2 * 4;
    u16* xl_n = (u16*)w; w += (size_t)N * 256 * 2;
    u16* xr_n = (u16*)w; w += (size_t)N * 256 * 2;
    u16* xl_e = (u16*)w; w += (size_t)E * 128 * 2;
    u16* proj = (u16*)w; w += (size_t)N * 128 * 2;
    float* alpha_n = (float*)w; w += (size_t)E * 4 * 4;
    u16* Wlt  = (u16*)w; w += (size_t)65536 * 2;
    u16* Wrt  = (u16*)w; w += (size_t)65536 * 2;
    u16* Wet  = (u16*)w; w += (size_t)32768 * 2;
    u16* Wl2t = (u16*)w; w += (size_t)16384 * 2;
    u16* Wr2t = (u16*)w; w += (size_t)16384 * 2;
    u16* We2t = (u16*)w; w += (size_t)32768 * 2;

    hipMemsetAsync(d_ws, 0, (size_t)(N + E) * 4, stream);

    // ---- prep + CSR builds ----
    k_prep<<<896, 256, 0, stream>>>(n2n_Wl, n2n_Wr, n2n_We, e2n_Wl, e2n_Wr, e2n_We,
                                    Wlt, Wrt, Wet, Wl2t, Wr2t, We2t);
    k_hist<<<E / 256, 256, 0, stream>>>(node_adj + E, cnt1, E);
    k_scan<<<1, 256, 0, stream>>>(cnt1, off1, cur1, N);
    k_scatter<<<E / 256, 256, 0, stream>>>(node_adj + E, cur1, eid1, E);
    k_hist<<<E2 / 256, 256, 0, stream>>>(edge_adj + E2, cnt2, E2);
    k_scan<<<1, 256, 0, stream>>>(cnt2, off2, cur2, E);
    k_scatter<<<E2 / 256, 256, 0, stream>>>(edge_adj + E2, cur2, eid2, E2);

    // ---- layer 1 ----
    k_node_gemm<<<N / 32, 256, 0, stream>>>(x_node, x_log, Wlt, n2n_bl, Wrt, n2n_br,
                                            xl_n, xr_n);
    k_edge_alpha1<<<E / 32, 256, 0, stream>>>(x_trace, node_adj, xl_n, xr_n,
                                              Wet, n2n_att, alpha_n);
    k_fused1<<<N / 4, 256, 0, stream>>>(node_adj, off1, eid1, alpha_n, xl_n, n2n_bias, out);

    // ---- layer 2 ----
    k_proj_gemm<<<N / 32, 256, 0, stream>>>(out, We2t, proj);
    k_trace_gemm<<<E / 32, 256, 0, stream>>>(x_trace, Wl2t, e2n_bl, Wr2t, e2n_br,
                                             xl_e, out + XT_OFF);
    k_fused2<<<E / 4, 256, 0, stream>>>(edge_adj, efea, off2, eid2, xl_e, proj,
                                        e2n_att, e2n_bias, out);
}